// Round 4
// baseline (132.327 us; speedup 1.0000x reference)
//
#include <hip/hip_runtime.h>
#include <hip/hip_bf16.h>

#define T_TOK 2048
#define H_DIM 1024
#define I_DIM 768
#define NEXP  8

typedef short bf16x8  __attribute__((ext_vector_type(8)));
typedef short short4v __attribute__((ext_vector_type(4)));
typedef float f32x4   __attribute__((ext_vector_type(4)));

__device__ __forceinline__ short f2bf(float f) {
  __bf16 b = (__bf16)f;              // RNE; pairs pack into v_cvt_pk_bf16_f32
  return __builtin_bit_cast(short, b);
}

__device__ __forceinline__ void gload16(const void* g, void* l) {
  __builtin_amdgcn_global_load_lds(
      (const __attribute__((address_space(1))) void*)g,
      (__attribute__((address_space(3))) void*)l, 16, 0, 0);
}

// ---------------- ws layout, bytes ----------------
// 0: counts[8] | 64: pads[8] | 128: bases[8] | 256: lists[8*2048]
// 131072: wbf = gate_bf(6291456) ++ up_bf(6291456) ++ down_bf(6291456) shorts
// 37879808: xc (5120*1024 shorts) | 48365568: h (5120*768 shorts) | end 56229888
#define WPE 6291456   // weight elems per array

// ---- routing compaction + prefix bases (1 block, 8 waves)
__global__ void moe_compact(const float* __restrict__ routw, int* __restrict__ wsI) {
  int lane = threadIdx.x & 63;
  int e    = threadIdx.x >> 6;
  int base = 0;
  for (int t0 = 0; t0 < T_TOK; t0 += 64) {
    float w = routw[(size_t)(t0 + lane) * NEXP + e];
    unsigned long long mask = __ballot(w > 0.0f);
    if (w > 0.0f) {
      int pos = __popcll(mask & ((1ull << lane) - 1));
      wsI[64 + e * T_TOK + base + pos] = t0 + lane;
    }
    base += __popcll(mask);
  }
  if (lane == 0) wsI[e] = base;
  __syncthreads();
  if (threadIdx.x == 0) {
    int acc = 0;
    for (int i = 0; i < NEXP; ++i) {
      int c = wsI[i];
      int p = (c + 127) & ~127;
      wsI[16 + i] = p;      // pads
      wsI[32 + i] = acc;    // bases
      acc += p;
    }
  }
}

// ---- weight fp32->bf16 convert (grid 2304 x 512, exact cover)
__global__ __launch_bounds__(512) void wconv(const float* __restrict__ g,
                                             const float* __restrict__ u,
                                             const float* __restrict__ d,
                                             unsigned short* __restrict__ wbf) {
  int gid = blockIdx.x * 512 + threadIdx.x;   // 1179648 groups of 16 elems
  int a = gid / 393216;                       // 0:gate 1:up 2:down
  int rem = (gid - a * 393216) * 16;
  const float* s = (a == 0) ? g : (a == 1) ? u : d;
  unsigned short* o = wbf + (size_t)a * WPE + rem;
#pragma unroll
  for (int j = 0; j < 4; ++j) {
    float4 v = *(const float4*)(s + rem + j * 4);
    short4v b = {f2bf(v.x), f2bf(v.y), f2bf(v.z), f2bf(v.w)};
    *(short4v*)(o + j * 4) = b;
  }
}

// ---- gather+convert x rows into compacted bf16 (zero-pad to pads[e])
__global__ __launch_bounds__(256) void xgather(const float* __restrict__ x,
                                               const int* __restrict__ wsI,
                                               unsigned short* __restrict__ xc) {
  int e = blockIdx.x >> 5, c = blockIdx.x & 31;
  int cnt = wsI[e], pad = wsI[16 + e], base = wsI[32 + e];
  int r0 = c * 64;
  if (r0 >= pad) return;
  int t = threadIdx.x;
  int r1 = min(r0 + 64, pad);
  for (int r = r0; r < r1; ++r) {
    unsigned short* dst = xc + (size_t)(base + r) * H_DIM + t * 4;
    if (r < cnt) {
      int tok = wsI[64 + e * T_TOK + r];
      float4 v = *(const float4*)(x + (size_t)tok * H_DIM + t * 4);
      short4v b = {f2bf(v.x), f2bf(v.y), f2bf(v.z), f2bf(v.w)};
      *(short4v*)dst = b;
    } else {
      short4v z = {0, 0, 0, 0};
      *(short4v*)dst = z;
    }
  }
}

// ---- gemm1: h = silu(Xc Wg^T)*(Xc Wu^T). Tile 64x128, BK=32, 256thr/4 waves.
// Per wave: 64x32 output, dual G/U -> 16 MFMA : 8 ds_read per K-step.
// grid = 8e * 32mt * 6nt = 1536 (e = bid&7 -> XCD pinning).
__global__ __launch_bounds__(256, 3) void moe_gemm1a(
    const unsigned short* __restrict__ xc, const unsigned short* __restrict__ wbf,
    const int* __restrict__ wsI, unsigned short* __restrict__ h) {
  int e = blockIdx.x & 7, r = blockIdx.x >> 3;
  int mt = r & 31, nt = r >> 5;              // mt 0..31, nt 0..5
  int cnt = wsI[e];
  int m0 = mt * 64;
  if (m0 >= cnt) return;
  int base = wsI[32 + e];
  int n0 = nt * 128;

  __shared__ unsigned short ls[2][10240];    // A[64][32]@0, G[128][32]@2048, U[128][32]@6144

  int tid = threadIdx.x, lane = tid & 63, wid = tid >> 6;   // wid 0..3 (N-split)
  int fr = lane & 15, fg = lane >> 4;
  int srow = lane >> 2, scol = (lane & 3) * 8;

  const unsigned short* gate_bf = wbf;
  const unsigned short* up_bf   = wbf + WPE;

  // staging: 20 chunks of 1KB (16 rows x 64B); wave w takes chunks w, w+4, ..., w+16
  const unsigned short* src[5];
  int ldo[5];
#pragma unroll
  for (int i = 0; i < 5; ++i) {
    int c = wid + 4 * i;
    ldo[i] = c * 512;    // shorts, wave-uniform; HW adds lane*16B
    if (c < 4)       src[i] = xc + (size_t)(base + m0 + 16 * c + srow) * H_DIM + scol;
    else if (c < 12) src[i] = gate_bf + (size_t)(e * I_DIM + n0 + 16 * (c - 4) + srow) * H_DIM + scol;
    else             src[i] = up_bf   + (size_t)(e * I_DIM + n0 + 16 * (c - 12) + srow) * H_DIM + scol;
  }

  f32x4 accG[4][2] = {};
  f32x4 accU[4][2] = {};

#pragma unroll
  for (int i = 0; i < 5; ++i) gload16(src[i], &ls[0][ldo[i]]);
  __syncthreads();

  for (int k = 0; k < H_DIM / 32; ++k) {
    int cur = k & 1;
    if (k + 1 < H_DIM / 32) {
#pragma unroll
      for (int i = 0; i < 5; ++i) gload16(src[i] + (k + 1) * 32, &ls[cur ^ 1][ldo[i]]);
    }
    bf16x8 af[4], gf[2], uf[2];
#pragma unroll
    for (int m = 0; m < 4; ++m)
      af[m] = *(const bf16x8*)&ls[cur][(m * 16 + fr) * 32 + fg * 8];
#pragma unroll
    for (int n = 0; n < 2; ++n) {
      gf[n] = *(const bf16x8*)&ls[cur][2048 + (wid * 32 + n * 16 + fr) * 32 + fg * 8];
      uf[n] = *(const bf16x8*)&ls[cur][6144 + (wid * 32 + n * 16 + fr) * 32 + fg * 8];
    }
#pragma unroll
    for (int m = 0; m < 4; ++m)
#pragma unroll
      for (int n = 0; n < 2; ++n) {
        accG[m][n] = __builtin_amdgcn_mfma_f32_16x16x32_bf16(af[m], gf[n], accG[m][n], 0, 0, 0);
        accU[m][n] = __builtin_amdgcn_mfma_f32_16x16x32_bf16(af[m], uf[n], accU[m][n], 0, 0, 0);
      }
    __syncthreads();   // minimal 2-phase: one vmcnt0+barrier per K-step, after MFMA
  }

#pragma unroll
  for (int m = 0; m < 4; ++m)
#pragma unroll
    for (int j = 0; j < 4; ++j) {
      int row = m * 16 + fg * 4 + j;         // C/D: col=lane&15, row=(lane>>4)*4+reg
      size_t rowbase = (size_t)(base + m0 + row) * I_DIM + n0 + wid * 32;
#pragma unroll
      for (int n = 0; n < 2; ++n) {
        float g = accG[m][n][j];
        float u = accU[m][n][j];
        h[rowbase + n * 16 + fr] = (unsigned short)f2bf(g * u / (1.f + __expf(-g)));
      }
    }
}

// ---- gemm2: out[t] += w * (h_e down^T). Tile 64x128, BK=32, 128thr/2 waves.
// Per wave: 32x128 output -> 16 MFMA : 10 ds_read per K-step. LDS 24KB -> ~6 blocks/CU.
// grid = 8e * 32mt * 8nt = 2048.
__global__ __launch_bounds__(128, 3) void moe_gemm2a(
    const unsigned short* __restrict__ h, const unsigned short* __restrict__ wbf,
    const int* __restrict__ wsI, const float* __restrict__ routw,
    float* __restrict__ out) {
  int e = blockIdx.x & 7, r = blockIdx.x >> 3;
  int mt = r & 31, nt = r >> 5;              // mt 0..31, nt 0..7
  int cnt = wsI[e];
  int m0 = mt * 64;
  if (m0 >= cnt) return;
  int base = wsI[32 + e];
  int n0 = nt * 128;
  const unsigned short* down_bf = wbf + 2 * WPE;

  __shared__ unsigned short ls[2][6144];     // A[64][32]@0, B[128][32]@2048

  int tid = threadIdx.x, lane = tid & 63, wid = tid >> 6;   // wid 0..1 (M-split)
  int fr = lane & 15, fg = lane >> 4;
  int srow = lane >> 2, scol = (lane & 3) * 8;

  // staging: 12 chunks of 1KB; wave w takes chunks w, w+2, ..., w+10
  const unsigned short* src[6];
  int ldo[6];
#pragma unroll
  for (int i = 0; i < 6; ++i) {
    int c = wid + 2 * i;
    ldo[i] = c * 512;
    if (c < 4) src[i] = h + (size_t)(base + m0 + 16 * c + srow) * I_DIM + scol;
    else       src[i] = down_bf + (size_t)(e * H_DIM + n0 + 16 * (c - 4) + srow) * I_DIM + scol;
  }

  f32x4 acc[2][8] = {};

#pragma unroll
  for (int i = 0; i < 6; ++i) gload16(src[i], &ls[0][ldo[i]]);
  __syncthreads();

  for (int k = 0; k < I_DIM / 32; ++k) {
    int cur = k & 1;
    if (k + 1 < I_DIM / 32) {
#pragma unroll
      for (int i = 0; i < 6; ++i) gload16(src[i] + (k + 1) * 32, &ls[cur ^ 1][ldo[i]]);
    }
    bf16x8 af[2], bf[8];
#pragma unroll
    for (int m = 0; m < 2; ++m)
      af[m] = *(const bf16x8*)&ls[cur][(wid * 32 + m * 16 + fr) * 32 + fg * 8];
#pragma unroll
    for (int n = 0; n < 8; ++n)
      bf[n] = *(const bf16x8*)&ls[cur][2048 + (n * 16 + fr) * 32 + fg * 8];
#pragma unroll
    for (int m = 0; m < 2; ++m)
#pragma unroll
      for (int n = 0; n < 8; ++n)
        acc[m][n] = __builtin_amdgcn_mfma_f32_16x16x32_bf16(af[m], bf[n], acc[m][n], 0, 0, 0);
    __syncthreads();
  }

#pragma unroll
  for (int m = 0; m < 2; ++m)
#pragma unroll
    for (int j = 0; j < 4; ++j) {
      int row = wid * 32 + m * 16 + fg * 4 + j;
      int grow = m0 + row;
      if (grow < cnt) {
        int t = wsI[64 + e * T_TOK + grow];
        float w = routw[(size_t)t * NEXP + e];
        float* orow = out + (size_t)t * H_DIM + n0;
#pragma unroll
        for (int n = 0; n < 8; ++n)
          atomicAdd(orow + n * 16 + fr, acc[m][n][j] * w);
      }
    }
}

extern "C" void kernel_launch(void* const* d_in, const int* in_sizes, int n_in,
                              void* d_out, int out_size, void* d_ws, size_t ws_size,
                              hipStream_t stream) {
  const float* x      = (const float*)d_in[0];
  const float* gate_w = (const float*)d_in[1];
  const float* up_w   = (const float*)d_in[2];
  const float* down_w = (const float*)d_in[3];
  const float* routw  = (const float*)d_in[4];
  float* out = (float*)d_out;
  int* wsI = (int*)d_ws;

  unsigned short* wbf = (unsigned short*)((char*)d_ws + 131072);
  unsigned short* xc  = (unsigned short*)((char*)d_ws + 37879808);
  unsigned short* h   = (unsigned short*)((char*)d_ws + 48365568);

  hipMemsetAsync(d_out, 0, (size_t)out_size * sizeof(float), stream);
  moe_compact<<<1, 512, 0, stream>>>(routw, wsI);
  wconv<<<2304, 512, 0, stream>>>(gate_w, up_w, down_w, wbf);
  xgather<<<256, 256, 0, stream>>>(x, wsI, xc);
  moe_gemm1a<<<8 * 32 * 6, 256, 0, stream>>>(xc, wbf, wsI, h);
  moe_gemm2a<<<8 * 32 * 8, 128, 0, stream>>>(h, wbf, wsI, routw, out);
}

// Round 5
// 122.125 us; speedup vs baseline: 1.0835x; 1.0835x over previous
//
#include <hip/hip_runtime.h>
#include <hip/hip_bf16.h>

#define T_TOK 2048
#define H_DIM 1024
#define I_DIM 768
#define NEXP  8

typedef short bf16x8  __attribute__((ext_vector_type(8)));
typedef short short4v __attribute__((ext_vector_type(4)));
typedef float f32x4   __attribute__((ext_vector_type(4)));

__device__ __forceinline__ short f2bf(float f) {
  __bf16 b = (__bf16)f;              // RNE; pairs pack into v_cvt_pk_bf16_f32
  return __builtin_bit_cast(short, b);
}

__device__ __forceinline__ void gload16(const void* g, void* l) {
  __builtin_amdgcn_global_load_lds(
      (const __attribute__((address_space(1))) void*)g,
      (__attribute__((address_space(3))) void*)l, 16, 0, 0);
}

// 16B-group XOR swizzle: spreads 64B-stride rows across all 8 bank groups
// (residual 2-way alias = free, m136). Same involution on stage-source & read.
__device__ __forceinline__ int swz_grp(int row, int g) {
  return g ^ (row & 3) ^ ((row >> 2) & 1);
}

// ---------------- ws layout, bytes ----------------
// 0: counts[8] | 64: pads[8] | 128: bases[8] | 256: lists[8*2048]
// 131072: wbf = gate_bf(6291456) ++ up_bf(6291456) ++ down_bf(6291456) shorts
// 37879808: xc (5120*1024 shorts) | 48365568: h (5120*768 shorts) | end 56229888
#define WPE 6291456   // weight elems per array

// ---- routing compaction + prefix bases (1 block, 8 waves)
__global__ void moe_compact(const float* __restrict__ routw, int* __restrict__ wsI) {
  int lane = threadIdx.x & 63;
  int e    = threadIdx.x >> 6;
  int base = 0;
  for (int t0 = 0; t0 < T_TOK; t0 += 64) {
    float w = routw[(size_t)(t0 + lane) * NEXP + e];
    unsigned long long mask = __ballot(w > 0.0f);
    if (w > 0.0f) {
      int pos = __popcll(mask & ((1ull << lane) - 1));
      wsI[64 + e * T_TOK + base + pos] = t0 + lane;
    }
    base += __popcll(mask);
  }
  if (lane == 0) wsI[e] = base;
  __syncthreads();
  if (threadIdx.x == 0) {
    int acc = 0;
    for (int i = 0; i < NEXP; ++i) {
      int c = wsI[i];
      int p = (c + 127) & ~127;
      wsI[16 + i] = p;      // pads
      wsI[32 + i] = acc;    // bases
      acc += p;
    }
  }
}

// ---- weight fp32->bf16 convert (grid 2304 x 512, exact cover)
__global__ __launch_bounds__(512) void wconv(const float* __restrict__ g,
                                             const float* __restrict__ u,
                                             const float* __restrict__ d,
                                             unsigned short* __restrict__ wbf) {
  int gid = blockIdx.x * 512 + threadIdx.x;   // 1179648 groups of 16 elems
  int a = gid / 393216;                       // 0:gate 1:up 2:down
  int rem = (gid - a * 393216) * 16;
  const float* s = (a == 0) ? g : (a == 1) ? u : d;
  unsigned short* o = wbf + (size_t)a * WPE + rem;
#pragma unroll
  for (int j = 0; j < 4; ++j) {
    float4 v = *(const float4*)(s + rem + j * 4);
    short4v b = {f2bf(v.x), f2bf(v.y), f2bf(v.z), f2bf(v.w)};
    *(short4v*)(o + j * 4) = b;
  }
}

// ---- gather+convert x rows into compacted bf16 (zero-pad to pads[e])
__global__ __launch_bounds__(256) void xgather(const float* __restrict__ x,
                                               const int* __restrict__ wsI,
                                               unsigned short* __restrict__ xc) {
  int e = blockIdx.x >> 5, c = blockIdx.x & 31;
  int cnt = wsI[e], pad = wsI[16 + e], base = wsI[32 + e];
  int r0 = c * 64;
  if (r0 >= pad) return;
  int t = threadIdx.x;
  int r1 = min(r0 + 64, pad);
  for (int r = r0; r < r1; ++r) {
    unsigned short* dst = xc + (size_t)(base + r) * H_DIM + t * 4;
    if (r < cnt) {
      int tok = wsI[64 + e * T_TOK + r];
      float4 v = *(const float4*)(x + (size_t)tok * H_DIM + t * 4);
      short4v b = {f2bf(v.x), f2bf(v.y), f2bf(v.z), f2bf(v.w)};
      *(short4v*)dst = b;
    } else {
      short4v z = {0, 0, 0, 0};
      *(short4v*)dst = z;
    }
  }
}

// ---- gemm1: h = silu(Xc Wg^T)*(Xc Wu^T). Tile 128x96, BK=32, 256thr/4 waves.
// Wave tile 64x48 dual G/U -> 24 MFMA : 10 ds_read. Depth-3 LDS ring (60KB),
// counted vmcnt(5) (never 0 mid-loop). grid = 8e * 16mt * 8nt = 1024.
__global__ __launch_bounds__(256, 2) void moe_gemm1a(
    const unsigned short* __restrict__ xc, const unsigned short* __restrict__ wbf,
    const int* __restrict__ wsI, unsigned short* __restrict__ h) {
  int e = blockIdx.x & 7, r = blockIdx.x >> 3;
  int mt = r & 15, nt = r >> 4;              // mt 0..15, nt 0..7
  int cnt = wsI[e];
  int m0 = mt * 128;
  if (m0 >= cnt) return;
  int base = wsI[32 + e];
  int n0 = nt * 96;

  // buffer: A[128][32]@0B, G[96][32]@8192B, U[96][32]@14336B; 20KB x 3
  __shared__ unsigned short ls[3][10240];

  int tid = threadIdx.x, lane = tid & 63, wid = tid >> 6;
  int wm = wid >> 1, wn = wid & 1;           // 2x2 wave grid -> 64x48 per wave
  int fr = lane & 15, fg = lane >> 4;

  const unsigned short* gate_bf = wbf;
  const unsigned short* up_bf   = wbf + WPE;

  // staging: 20 chunks of 1KB (16 rows x 64B); wave w takes chunks w+4i, i=0..4.
  // source col pre-swizzled so linear gload_lds dest lands swizzled data.
  int srow = lane >> 2;
  int scol = swz_grp(srow, lane & 3) * 8;
  const unsigned short* src[5];
  int ldo[5];
#pragma unroll
  for (int i = 0; i < 5; ++i) {
    int c = wid + 4 * i;
    ldo[i] = c * 512;                        // shorts; wave-uniform
    if (c < 8)       src[i] = xc + (size_t)(base + m0 + 16 * c + srow) * H_DIM + scol;
    else if (c < 14) src[i] = gate_bf + (size_t)(e * I_DIM + n0 + 16 * (c - 8) + srow) * H_DIM + scol;
    else             src[i] = up_bf   + (size_t)(e * I_DIM + n0 + 16 * (c - 14) + srow) * H_DIM + scol;
  }

  // per-lane swizzled read offsets (shorts), constant across K-steps
  int offA[4], offG[3], offU[3];
#pragma unroll
  for (int m = 0; m < 4; ++m) {
    int rr = wm * 64 + m * 16 + fr;
    offA[m] = rr * 32 + (swz_grp(rr, fg) << 3);
  }
#pragma unroll
  for (int n = 0; n < 3; ++n) {
    int rr = wn * 48 + n * 16 + fr;
    int sw = rr * 32 + (swz_grp(rr, fg) << 3);
    offG[n] = 4096 + sw;
    offU[n] = 7168 + sw;
  }

  f32x4 accG[4][3] = {};
  f32x4 accU[4][3] = {};

#pragma unroll
  for (int i = 0; i < 5; ++i) gload16(src[i], &ls[0][ldo[i]]);
#pragma unroll
  for (int i = 0; i < 5; ++i) gload16(src[i] + 32, &ls[1][ldo[i]]);
  asm volatile("s_waitcnt vmcnt(5)" ::: "memory");
  __builtin_amdgcn_s_barrier();
  __builtin_amdgcn_sched_barrier(0);

  int cur = 0, wrb = 2;
  for (int k = 0; k < 32; ++k) {
    const unsigned short* bufp = ls[cur];
    bf16x8 af[4], gf[3], uf[3];
#pragma unroll
    for (int m = 0; m < 4; ++m) af[m] = *(const bf16x8*)(bufp + offA[m]);
#pragma unroll
    for (int n = 0; n < 3; ++n) {
      gf[n] = *(const bf16x8*)(bufp + offG[n]);
      uf[n] = *(const bf16x8*)(bufp + offU[n]);
    }
#pragma unroll
    for (int m = 0; m < 4; ++m)
#pragma unroll
      for (int n = 0; n < 3; ++n) {
        accG[m][n] = __builtin_amdgcn_mfma_f32_16x16x32_bf16(af[m], gf[n], accG[m][n], 0, 0, 0);
        accU[m][n] = __builtin_amdgcn_mfma_f32_16x16x32_bf16(af[m], uf[n], accU[m][n], 0, 0, 0);
      }
    if (k + 2 < 32) {
#pragma unroll
      for (int i = 0; i < 5; ++i) gload16(src[i] + (k + 2) * 32, &ls[wrb][ldo[i]]);
      asm volatile("s_waitcnt vmcnt(5)" ::: "memory");   // stage(k+1) landed; stage(k+2) stays in flight
    } else {
      asm volatile("s_waitcnt vmcnt(0)" ::: "memory");   // tail drain
    }
    __builtin_amdgcn_s_barrier();
    __builtin_amdgcn_sched_barrier(0);
    cur = (cur == 2) ? 0 : cur + 1;
    wrb = (wrb == 2) ? 0 : wrb + 1;
  }

#pragma unroll
  for (int m = 0; m < 4; ++m)
#pragma unroll
    for (int j = 0; j < 4; ++j) {
      int row = wm * 64 + m * 16 + fg * 4 + j;   // C/D: col=lane&15, row=(lane>>4)*4+reg
      size_t rowbase = (size_t)(base + m0 + row) * I_DIM + n0 + wn * 48;
#pragma unroll
      for (int n = 0; n < 3; ++n) {
        float g = accG[m][n][j];
        float u = accU[m][n][j];
        h[rowbase + n * 16 + fr] = (unsigned short)f2bf(g * u / (1.f + __expf(-g)));
      }
    }
}

// ---- gemm2: out[t] += w * (h_e down^T). Tile 128x128, BK=32, 256thr/4 waves.
// Wave tile 64x64 -> 16 MFMA : 8 ds_read. Depth-3 ring (48KB), counted vmcnt(4).
// grid = 8e * 16mt * 8nt = 1024.
__global__ __launch_bounds__(256, 3) void moe_gemm2a(
    const unsigned short* __restrict__ h, const unsigned short* __restrict__ wbf,
    const int* __restrict__ wsI, const float* __restrict__ routw,
    float* __restrict__ out) {
  int e = blockIdx.x & 7, r = blockIdx.x >> 3;
  int mt = r & 15, nt = r >> 4;
  int cnt = wsI[e];
  int m0 = mt * 128;
  if (m0 >= cnt) return;
  int base = wsI[32 + e];
  int n0 = nt * 128;
  const unsigned short* down_bf = wbf + 2 * WPE;

  // buffer: A[128][32]@0B, B[128][32]@8192B; 16KB x 3
  __shared__ unsigned short ls[3][8192];

  int tid = threadIdx.x, lane = tid & 63, wid = tid >> 6;
  int wm = wid >> 1, wn = wid & 1;
  int fr = lane & 15, fg = lane >> 4;

  int srow = lane >> 2;
  int scol = swz_grp(srow, lane & 3) * 8;
  const unsigned short* src[4];
  int ldo[4];
#pragma unroll
  for (int i = 0; i < 4; ++i) {
    int c = wid + 4 * i;
    ldo[i] = c * 512;
    if (c < 8) src[i] = h + (size_t)(base + m0 + 16 * c + srow) * I_DIM + scol;
    else       src[i] = down_bf + (size_t)(e * H_DIM + n0 + 16 * (c - 8) + srow) * I_DIM + scol;
  }

  int offA[4], offB[4];
#pragma unroll
  for (int m = 0; m < 4; ++m) {
    int rr = wm * 64 + m * 16 + fr;
    offA[m] = rr * 32 + (swz_grp(rr, fg) << 3);
  }
#pragma unroll
  for (int n = 0; n < 4; ++n) {
    int rr = wn * 64 + n * 16 + fr;
    offB[n] = 4096 + rr * 32 + (swz_grp(rr, fg) << 3);
  }

  f32x4 acc[4][4] = {};

#pragma unroll
  for (int i = 0; i < 4; ++i) gload16(src[i], &ls[0][ldo[i]]);
#pragma unroll
  for (int i = 0; i < 4; ++i) gload16(src[i] + 32, &ls[1][ldo[i]]);
  asm volatile("s_waitcnt vmcnt(4)" ::: "memory");
  __builtin_amdgcn_s_barrier();
  __builtin_amdgcn_sched_barrier(0);

  int cur = 0, wrb = 2;
  for (int k = 0; k < 24; ++k) {
    const unsigned short* bufp = ls[cur];
    bf16x8 af[4], bf[4];
#pragma unroll
    for (int m = 0; m < 4; ++m) af[m] = *(const bf16x8*)(bufp + offA[m]);
#pragma unroll
    for (int n = 0; n < 4; ++n) bf[n] = *(const bf16x8*)(bufp + offB[n]);
#pragma unroll
    for (int m = 0; m < 4; ++m)
#pragma unroll
      for (int n = 0; n < 4; ++n)
        acc[m][n] = __builtin_amdgcn_mfma_f32_16x16x32_bf16(af[m], bf[n], acc[m][n], 0, 0, 0);
    if (k + 2 < 24) {
#pragma unroll
      for (int i = 0; i < 4; ++i) gload16(src[i] + (k + 2) * 32, &ls[wrb][ldo[i]]);
      asm volatile("s_waitcnt vmcnt(4)" ::: "memory");
    } else {
      asm volatile("s_waitcnt vmcnt(0)" ::: "memory");
    }
    __builtin_amdgcn_s_barrier();
    __builtin_amdgcn_sched_barrier(0);
    cur = (cur == 2) ? 0 : cur + 1;
    wrb = (wrb == 2) ? 0 : wrb + 1;
  }

#pragma unroll
  for (int m = 0; m < 4; ++m)
#pragma unroll
    for (int j = 0; j < 4; ++j) {
      int row = wm * 64 + m * 16 + fg * 4 + j;
      int grow = m0 + row;
      if (grow < cnt) {
        int t = wsI[64 + e * T_TOK + grow];
        float w = routw[(size_t)t * NEXP + e];
        float* orow = out + (size_t)t * H_DIM + n0 + wn * 64;
#pragma unroll
        for (int n = 0; n < 4; ++n)
          atomicAdd(orow + n * 16 + fr, acc[m][n][j] * w);
      }
    }
}

extern "C" void kernel_launch(void* const* d_in, const int* in_sizes, int n_in,
                              void* d_out, int out_size, void* d_ws, size_t ws_size,
                              hipStream_t stream) {
  const float* x      = (const float*)d_in[0];
  const float* gate_w = (const float*)d_in[1];
  const float* up_w   = (const float*)d_in[2];
  const float* down_w = (const float*)d_in[3];
  const float* routw  = (const float*)d_in[4];
  float* out = (float*)d_out;
  int* wsI = (int*)d_ws;

  unsigned short* wbf = (unsigned short*)((char*)d_ws + 131072);
  unsigned short* xc  = (unsigned short*)((char*)d_ws + 37879808);
  unsigned short* h   = (unsigned short*)((char*)d_ws + 48365568);

  hipMemsetAsync(d_out, 0, (size_t)out_size * sizeof(float), stream);
  moe_compact<<<1, 512, 0, stream>>>(routw, wsI);
  wconv<<<2304, 512, 0, stream>>>(gate_w, up_w, down_w, wbf);
  xgather<<<256, 256, 0, stream>>>(x, wsI, xc);
  moe_gemm1a<<<8 * 16 * 8, 256, 0, stream>>>(xc, wbf, wsI, h);
  moe_gemm2a<<<8 * 16 * 8, 256, 0, stream>>>(h, wbf, wsI, routw, out);
}

// Round 6
// 118.493 us; speedup vs baseline: 1.1167x; 1.0307x over previous
//
#include <hip/hip_runtime.h>
#include <hip/hip_bf16.h>

#define T_TOK 2048
#define H_DIM 1024
#define I_DIM 768
#define NEXP  8

typedef short bf16x8  __attribute__((ext_vector_type(8)));
typedef short short4v __attribute__((ext_vector_type(4)));
typedef float f32x4   __attribute__((ext_vector_type(4)));

__device__ __forceinline__ short f2bf(float f) {
  __bf16 b = (__bf16)f;              // RNE; pairs pack into v_cvt_pk_bf16_f32
  return __builtin_bit_cast(short, b);
}

__device__ __forceinline__ void gload16(const void* g, void* l) {
  __builtin_amdgcn_global_load_lds(
      (const __attribute__((address_space(1))) void*)g,
      (__attribute__((address_space(3))) void*)l, 16, 0, 0);
}

// 16B-group XOR swizzle (kept from r5: harmless, small gain). Same involution
// on stage-source col and read col.
__device__ __forceinline__ int swz_grp(int row, int g) {
  return g ^ (row & 3) ^ ((row >> 2) & 1);
}

// ---------------- ws layout, bytes ----------------
// 0: counts[8] | 64: pads[8] | 128: bases[8] | 256: lists[8*2048]
// 131072: wbf = gate_bf(6291456) ++ up_bf(6291456) ++ down_bf(6291456) shorts
// 37879808: xc (5120*1024 shorts) | 48365568: h (5120*768 shorts) | end 56229888
#define WPE 6291456   // weight elems per array

// ---- fast zero-fill for d_out (replaces 39.7us runtime fillBuffer)
__global__ __launch_bounds__(256) void zerofill(float* __restrict__ p, int n4) {
  int i = (blockIdx.x * 256 + threadIdx.x) * 2;   // two float4 per thread
  f32x4 z = {0.f, 0.f, 0.f, 0.f};
  if (i < n4)     *(f32x4*)(p + i * 4) = z;
  if (i + 1 < n4) *(f32x4*)(p + i * 4 + 4) = z;
}

// ---- routing compaction + prefix bases (1 block, 8 waves)
__global__ void moe_compact(const float* __restrict__ routw, int* __restrict__ wsI) {
  int lane = threadIdx.x & 63;
  int e    = threadIdx.x >> 6;
  int base = 0;
  for (int t0 = 0; t0 < T_TOK; t0 += 64) {
    float w = routw[(size_t)(t0 + lane) * NEXP + e];
    unsigned long long mask = __ballot(w > 0.0f);
    if (w > 0.0f) {
      int pos = __popcll(mask & ((1ull << lane) - 1));
      wsI[64 + e * T_TOK + base + pos] = t0 + lane;
    }
    base += __popcll(mask);
  }
  if (lane == 0) wsI[e] = base;
  __syncthreads();
  if (threadIdx.x == 0) {
    int acc = 0;
    for (int i = 0; i < NEXP; ++i) {
      int c = wsI[i];
      int p = (c + 127) & ~127;
      wsI[16 + i] = p;      // pads
      wsI[32 + i] = acc;    // bases
      acc += p;
    }
  }
}

// ---- weight fp32->bf16 convert (grid 2304 x 512, exact cover)
__global__ __launch_bounds__(512) void wconv(const float* __restrict__ g,
                                             const float* __restrict__ u,
                                             const float* __restrict__ d,
                                             unsigned short* __restrict__ wbf) {
  int gid = blockIdx.x * 512 + threadIdx.x;   // 1179648 groups of 16 elems
  int a = gid / 393216;                       // 0:gate 1:up 2:down
  int rem = (gid - a * 393216) * 16;
  const float* s = (a == 0) ? g : (a == 1) ? u : d;
  unsigned short* o = wbf + (size_t)a * WPE + rem;
#pragma unroll
  for (int j = 0; j < 4; ++j) {
    float4 v = *(const float4*)(s + rem + j * 4);
    short4v b = {f2bf(v.x), f2bf(v.y), f2bf(v.z), f2bf(v.w)};
    *(short4v*)(o + j * 4) = b;
  }
}

// ---- gather+convert x rows into compacted bf16 (zero-pad to pads[e])
__global__ __launch_bounds__(256) void xgather(const float* __restrict__ x,
                                               const int* __restrict__ wsI,
                                               unsigned short* __restrict__ xc) {
  int e = blockIdx.x >> 5, c = blockIdx.x & 31;
  int cnt = wsI[e], pad = wsI[16 + e], base = wsI[32 + e];
  int r0 = c * 64;
  if (r0 >= pad) return;
  int t = threadIdx.x;
  int r1 = min(r0 + 64, pad);
  for (int r = r0; r < r1; ++r) {
    unsigned short* dst = xc + (size_t)(base + r) * H_DIM + t * 4;
    if (r < cnt) {
      int tok = wsI[64 + e * T_TOK + r];
      float4 v = *(const float4*)(x + (size_t)tok * H_DIM + t * 4);
      short4v b = {f2bf(v.x), f2bf(v.y), f2bf(v.z), f2bf(v.w)};
      *(short4v*)dst = b;
    } else {
      short4v z = {0, 0, 0, 0};
      *(short4v*)dst = z;
    }
  }
}

// ---- gemm1: h = silu(Xc Wg^T)*(Xc Wu^T). Tile 64x96, BK=32, 256thr/4 waves.
// Wave tile 32x48 dual G/U -> 12 MFMA : 8 ds_read. Depth-3 ring (48KB -> 3 blk/CU),
// counted vmcnt(4). grid = 8e*32mt*8nt = 2048 (~512 active = 2/CU).
__global__ __launch_bounds__(256, 3) void moe_gemm1a(
    const unsigned short* __restrict__ xc, const unsigned short* __restrict__ wbf,
    const int* __restrict__ wsI, unsigned short* __restrict__ h) {
  int e = blockIdx.x & 7, r = blockIdx.x >> 3;
  int mt = r & 31, nt = r >> 5;              // mt 0..31, nt 0..7
  int cnt = wsI[e];
  int m0 = mt * 64;
  if (m0 >= cnt) return;
  int base = wsI[32 + e];
  int n0 = nt * 96;

  // shorts: A[64][32]@0, G[96][32]@2048, U[96][32]@5120; 16KB x 3
  __shared__ unsigned short ls[3][8192];

  int tid = threadIdx.x, lane = tid & 63, wid = tid >> 6;
  int wm = wid >> 1, wn = wid & 1;           // 2x2 wave grid -> 32x48 per wave
  int fr = lane & 15, fg = lane >> 4;

  const unsigned short* gate_bf = wbf;
  const unsigned short* up_bf   = wbf + WPE;

  // staging: 16 chunks of 1KB (16 rows x 64B); wave w takes chunks w+4i, i=0..3
  int srow = lane >> 2;
  int scol = swz_grp(srow, lane & 3) * 8;
  const unsigned short* src[4];
  int ldo[4];
#pragma unroll
  for (int i = 0; i < 4; ++i) {
    int c = wid + 4 * i;
    ldo[i] = c * 512;                        // shorts; wave-uniform
    if (c < 4)       src[i] = xc + (size_t)(base + m0 + 16 * c + srow) * H_DIM + scol;
    else if (c < 10) src[i] = gate_bf + (size_t)(e * I_DIM + n0 + 16 * (c - 4) + srow) * H_DIM + scol;
    else             src[i] = up_bf   + (size_t)(e * I_DIM + n0 + 16 * (c - 10) + srow) * H_DIM + scol;
  }

  // per-lane swizzled read offsets (shorts), constant across K-steps
  int offA[2], offG[3], offU[3];
#pragma unroll
  for (int m = 0; m < 2; ++m) {
    int rr = wm * 32 + m * 16 + fr;
    offA[m] = rr * 32 + (swz_grp(rr, fg) << 3);
  }
#pragma unroll
  for (int n = 0; n < 3; ++n) {
    int rr = wn * 48 + n * 16 + fr;
    int sw = rr * 32 + (swz_grp(rr, fg) << 3);
    offG[n] = 2048 + sw;
    offU[n] = 5120 + sw;
  }

  f32x4 accG[2][3] = {};
  f32x4 accU[2][3] = {};

#pragma unroll
  for (int i = 0; i < 4; ++i) gload16(src[i], &ls[0][ldo[i]]);
#pragma unroll
  for (int i = 0; i < 4; ++i) gload16(src[i] + 32, &ls[1][ldo[i]]);
  asm volatile("s_waitcnt vmcnt(4)" ::: "memory");
  __builtin_amdgcn_s_barrier();
  __builtin_amdgcn_sched_barrier(0);

  int cur = 0, wrb = 2;
  for (int k = 0; k < 32; ++k) {
    const unsigned short* bufp = ls[cur];
    bf16x8 af[2], gf[3], uf[3];
#pragma unroll
    for (int m = 0; m < 2; ++m) af[m] = *(const bf16x8*)(bufp + offA[m]);
#pragma unroll
    for (int n = 0; n < 3; ++n) {
      gf[n] = *(const bf16x8*)(bufp + offG[n]);
      uf[n] = *(const bf16x8*)(bufp + offU[n]);
    }
#pragma unroll
    for (int m = 0; m < 2; ++m)
#pragma unroll
      for (int n = 0; n < 3; ++n) {
        accG[m][n] = __builtin_amdgcn_mfma_f32_16x16x32_bf16(af[m], gf[n], accG[m][n], 0, 0, 0);
        accU[m][n] = __builtin_amdgcn_mfma_f32_16x16x32_bf16(af[m], uf[n], accU[m][n], 0, 0, 0);
      }
    if (k + 2 < 32) {
#pragma unroll
      for (int i = 0; i < 4; ++i) gload16(src[i] + (k + 2) * 32, &ls[wrb][ldo[i]]);
      asm volatile("s_waitcnt vmcnt(4)" ::: "memory");   // k+1 landed; k+2 in flight
    } else {
      asm volatile("s_waitcnt vmcnt(0)" ::: "memory");   // tail drain
    }
    __builtin_amdgcn_s_barrier();
    __builtin_amdgcn_sched_barrier(0);
    cur = (cur == 2) ? 0 : cur + 1;
    wrb = (wrb == 2) ? 0 : wrb + 1;
  }

#pragma unroll
  for (int m = 0; m < 2; ++m)
#pragma unroll
    for (int j = 0; j < 4; ++j) {
      int row = wm * 32 + m * 16 + fg * 4 + j;   // C/D: col=lane&15, row=(lane>>4)*4+reg
      size_t rowbase = (size_t)(base + m0 + row) * I_DIM + n0 + wn * 48;
#pragma unroll
      for (int n = 0; n < 3; ++n) {
        float g = accG[m][n][j];
        float u = accU[m][n][j];
        h[rowbase + n * 16 + fr] = (unsigned short)f2bf(g * u / (1.f + __expf(-g)));
      }
    }
}

// ---- gemm2: out[t] += w * (h_e down^T). Tile 64x128, BK=32, 256thr/4 waves.
// Wave tile 32x64 -> 8 MFMA : 6 ds_read. Depth-3 ring (36KB -> 4 blk/CU),
// counted vmcnt(3). grid = 8e*32mt*8nt = 2048 (~512 active).
__global__ __launch_bounds__(256, 4) void moe_gemm2a(
    const unsigned short* __restrict__ h, const unsigned short* __restrict__ wbf,
    const int* __restrict__ wsI, const float* __restrict__ routw,
    float* __restrict__ out) {
  int e = blockIdx.x & 7, r = blockIdx.x >> 3;
  int mt = r & 31, nt = r >> 5;
  int cnt = wsI[e];
  int m0 = mt * 64;
  if (m0 >= cnt) return;
  int base = wsI[32 + e];
  int n0 = nt * 128;
  const unsigned short* down_bf = wbf + 2 * WPE;

  // shorts: A[64][32]@0, B[128][32]@2048; 12KB x 3
  __shared__ unsigned short ls[3][6144];

  int tid = threadIdx.x, lane = tid & 63, wid = tid >> 6;
  int wm = wid >> 1, wn = wid & 1;
  int fr = lane & 15, fg = lane >> 4;

  int srow = lane >> 2;
  int scol = swz_grp(srow, lane & 3) * 8;
  const unsigned short* src[3];
  int ldo[3];
#pragma unroll
  for (int i = 0; i < 3; ++i) {
    int c = wid + 4 * i;
    ldo[i] = c * 512;
    if (c < 4) src[i] = h + (size_t)(base + m0 + 16 * c + srow) * I_DIM + scol;
    else       src[i] = down_bf + (size_t)(e * H_DIM + n0 + 16 * (c - 4) + srow) * I_DIM + scol;
  }

  int offA[2], offB[4];
#pragma unroll
  for (int m = 0; m < 2; ++m) {
    int rr = wm * 32 + m * 16 + fr;
    offA[m] = rr * 32 + (swz_grp(rr, fg) << 3);
  }
#pragma unroll
  for (int n = 0; n < 4; ++n) {
    int rr = wn * 64 + n * 16 + fr;
    offB[n] = 2048 + rr * 32 + (swz_grp(rr, fg) << 3);
  }

  f32x4 acc[2][4] = {};

#pragma unroll
  for (int i = 0; i < 3; ++i) gload16(src[i], &ls[0][ldo[i]]);
#pragma unroll
  for (int i = 0; i < 3; ++i) gload16(src[i] + 32, &ls[1][ldo[i]]);
  asm volatile("s_waitcnt vmcnt(3)" ::: "memory");
  __builtin_amdgcn_s_barrier();
  __builtin_amdgcn_sched_barrier(0);

  int cur = 0, wrb = 2;
  for (int k = 0; k < 24; ++k) {
    const unsigned short* bufp = ls[cur];
    bf16x8 af[2], bf[4];
#pragma unroll
    for (int m = 0; m < 2; ++m) af[m] = *(const bf16x8*)(bufp + offA[m]);
#pragma unroll
    for (int n = 0; n < 4; ++n) bf[n] = *(const bf16x8*)(bufp + offB[n]);
#pragma unroll
    for (int m = 0; m < 2; ++m)
#pragma unroll
      for (int n = 0; n < 4; ++n)
        acc[m][n] = __builtin_amdgcn_mfma_f32_16x16x32_bf16(af[m], bf[n], acc[m][n], 0, 0, 0);
    if (k + 2 < 24) {
#pragma unroll
      for (int i = 0; i < 3; ++i) gload16(src[i] + (k + 2) * 32, &ls[wrb][ldo[i]]);
      asm volatile("s_waitcnt vmcnt(3)" ::: "memory");
    } else {
      asm volatile("s_waitcnt vmcnt(0)" ::: "memory");
    }
    __builtin_amdgcn_s_barrier();
    __builtin_amdgcn_sched_barrier(0);
    cur = (cur == 2) ? 0 : cur + 1;
    wrb = (wrb == 2) ? 0 : wrb + 1;
  }

#pragma unroll
  for (int m = 0; m < 2; ++m)
#pragma unroll
    for (int j = 0; j < 4; ++j) {
      int row = wm * 32 + m * 16 + fg * 4 + j;
      int grow = m0 + row;
      if (grow < cnt) {
        int t = wsI[64 + e * T_TOK + grow];
        float w = routw[(size_t)t * NEXP + e];
        float* orow = out + (size_t)t * H_DIM + n0 + wn * 64;
#pragma unroll
        for (int n = 0; n < 4; ++n)
          atomicAdd(orow + n * 16 + fr, acc[m][n][j] * w);
      }
    }
}

extern "C" void kernel_launch(void* const* d_in, const int* in_sizes, int n_in,
                              void* d_out, int out_size, void* d_ws, size_t ws_size,
                              hipStream_t stream) {
  const float* x      = (const float*)d_in[0];
  const float* gate_w = (const float*)d_in[1];
  const float* up_w   = (const float*)d_in[2];
  const float* down_w = (const float*)d_in[3];
  const float* routw  = (const float*)d_in[4];
  float* out = (float*)d_out;
  int* wsI = (int*)d_ws;

  unsigned short* wbf = (unsigned short*)((char*)d_ws + 131072);
  unsigned short* xc  = (unsigned short*)((char*)d_ws + 37879808);
  unsigned short* h   = (unsigned short*)((char*)d_ws + 48365568);

  int n4 = out_size / 4;   // 2M floats -> 524288 float4
  zerofill<<<(n4 / 2 + 255) / 256, 256, 0, stream>>>(out, n4);
  moe_compact<<<1, 512, 0, stream>>>(routw, wsI);
  wconv<<<2304, 512, 0, stream>>>(gate_w, up_w, down_w, wbf);
  xgather<<<256, 256, 0, stream>>>(x, wsI, xc);
  moe_gemm1a<<<8 * 32 * 8, 256, 0, stream>>>(xc, wbf, wsI, h);
  moe_gemm2a<<<8 * 32 * 8, 256, 0, stream>>>(h, wbf, wsI, routw, out);
}

// Round 7
// 92.094 us; speedup vs baseline: 1.4369x; 1.2866x over previous
//
#include <hip/hip_runtime.h>
#include <hip/hip_bf16.h>

#define T_TOK 2048
#define H_DIM 1024
#define I_DIM 768
#define NEXP  8
#define WPE   6291456   // weight elems per array (E*I*H)

typedef short bf16x8  __attribute__((ext_vector_type(8)));
typedef short short4v __attribute__((ext_vector_type(4)));
typedef float f32x4   __attribute__((ext_vector_type(4)));

__device__ __forceinline__ short f2bf(float f) {
  __bf16 b = (__bf16)f;
  return __builtin_bit_cast(short, b);
}
__device__ __forceinline__ void gload16(const void* g, void* l) {
  __builtin_amdgcn_global_load_lds(
      (const __attribute__((address_space(1))) void*)g,
      (__attribute__((address_space(3))) void*)l, 16, 0, 0);
}
__device__ __forceinline__ int padcnt(int c) { return (c + 127) & ~127; }
__device__ __forceinline__ int ebase(const int* __restrict__ cnts, int e) {
  int b = 0;
#pragma unroll
  for (int i = 0; i < NEXP; ++i)
    if (i < e) b += padcnt(cnts[i]);
  return b;
}

// ---------------- ws layout, bytes ----------------
// 0: counts[8] | 256: lists[8*2048 ints]
// 131072: wbf = gate_bf ++ up_bf ++ down_bf (shorts)
// 37879808: xc (5120*1024 shorts) | 48365568: h (5120*768 shorts)

// ---- prep: fused compact (blocks 0..7) + zerofill (8..1031) + wconv (1032..3335)
__global__ __launch_bounds__(512) void prep(const float* __restrict__ routw,
                                            const float* __restrict__ gw,
                                            const float* __restrict__ uw,
                                            const float* __restrict__ dw,
                                            unsigned short* __restrict__ wbf,
                                            float* __restrict__ out,
                                            int* __restrict__ wsI) {
  int bid = blockIdx.x, tid = threadIdx.x;
  if (bid < 8) {               // ---- compact, block e; wave w owns tokens [w*256, w*256+256)
    __shared__ int sc[8];
    int e = bid, lane = tid & 63, w = tid >> 6;
    unsigned long long mk[4];
    int cnt = 0;
#pragma unroll
    for (int c = 0; c < 4; ++c) {
      int tk = w * 256 + c * 64 + lane;
      float v = routw[(size_t)tk * NEXP + e];
      mk[c] = __ballot(v > 0.f);
      cnt += __popcll(mk[c]);
    }
    if (lane == 0) sc[w] = cnt;
    __syncthreads();
    int pre = 0;
#pragma unroll
    for (int j = 0; j < 8; ++j)
      if (j < w) pre += sc[j];
    int run = pre;
#pragma unroll
    for (int c = 0; c < 4; ++c) {
      int tk = w * 256 + c * 64 + lane;
      if ((mk[c] >> lane) & 1ull) {
        int pos = __popcll(mk[c] & ((1ull << lane) - 1));
        wsI[64 + e * T_TOK + run + pos] = tk;
      }
      run += __popcll(mk[c]);
    }
    if (w == 7 && lane == 0) wsI[e] = run;
  } else if (bid < 1032) {     // ---- zerofill out: 1024 blocks * 512 thr * 1 float4
    int i = (bid - 8) * 512 + tid;
    f32x4 z = {0.f, 0.f, 0.f, 0.f};
    *(f32x4*)(out + (size_t)i * 4) = z;
  } else {                     // ---- wconv fp32->bf16
    int gid = (bid - 1032) * 512 + tid;
    int a = gid / 393216;
    int rem = (gid - a * 393216) * 16;
    const float* s = (a == 0) ? gw : (a == 1) ? uw : dw;
    unsigned short* o = wbf + (size_t)a * WPE + rem;
#pragma unroll
    for (int j = 0; j < 4; ++j) {
      float4 v = *(const float4*)(s + rem + j * 4);
      short4v b = {f2bf(v.x), f2bf(v.y), f2bf(v.z), f2bf(v.w)};
      *(short4v*)(o + j * 4) = b;
    }
  }
}

// ---- xgather: fully parallel; block (e, rb) covers 4 rows; 64 thr/row * 16 shorts
__global__ __launch_bounds__(256) void xgather(const float* __restrict__ x,
                                               const int* __restrict__ wsI,
                                               unsigned short* __restrict__ xc) {
  int e = blockIdx.x >> 9;          // grid 8*512
  int rb = blockIdx.x & 511;
  int cnt = wsI[e];
  int pad = padcnt(cnt);
  int r = rb * 4 + (threadIdx.x >> 6);
  if (r >= pad) return;
  int base = ebase(wsI, e);
  int col = (threadIdx.x & 63) * 16;
  unsigned short* dst = xc + (size_t)(base + r) * H_DIM + col;
  if (r < cnt) {
    int tok = wsI[64 + e * T_TOK + r];
    const float* sr = x + (size_t)tok * H_DIM + col;
#pragma unroll
    for (int j = 0; j < 4; ++j) {
      float4 v = *(const float4*)(sr + j * 4);
      short4v b = {f2bf(v.x), f2bf(v.y), f2bf(v.z), f2bf(v.w)};
      *(short4v*)(dst + j * 4) = b;
    }
  } else {
#pragma unroll
    for (int j = 0; j < 4; ++j) {
      short4v z = {0, 0, 0, 0};
      *(short4v*)(dst + j * 4) = z;
    }
  }
}

// ---- gemm1: h = silu(Xc Wg^T)*(Xc Wu^T).
// Tile M128 x (128G+128U), BK=64, 512 thr/8 waves (2M x 4N), wave tile 64 x (32G+32U).
// Half-K phase pipeline: per phase {issue 3 stage loads, 8 ds_read, 16 MFMA, vmcnt(3), barrier}.
// LDS dbuf 2 x 48KB. grid = 8e * 16mt * 6nt = 768 (e=bid&7 -> XCD pin).
__global__ __launch_bounds__(512, 2) void moe_gemm1(
    const unsigned short* __restrict__ xc, const unsigned short* __restrict__ wbf,
    const int* __restrict__ wsI, unsigned short* __restrict__ h) {
  int e = blockIdx.x & 7, rr = blockIdx.x >> 3;
  int mt = rr & 15, nt = rr >> 4;       // nt 0..5
  int cnt = wsI[e];
  int m0 = mt * 128;
  if (m0 >= cnt) return;
  int base = ebase(wsI, e);
  int n0 = nt * 128;

  // shorts per buffer (24576 = 48KB): A kh0 @0, A kh1 @4096, B kh0 @8192, B kh1 @16384
  __shared__ unsigned short ls[2][24576];

  int tid = threadIdx.x, lane = tid & 63, w = tid >> 6;   // 8 waves
  int wm = w >> 2, wn = w & 3;
  int fr = lane & 15, fg = lane >> 4;

  const unsigned short* gate_bf = wbf;
  const unsigned short* up_bf   = wbf + WPE;

  // staging: per half, wave w does 3 x gload16 (A rows 16w.., G rows 16w.., U rows 16w..)
  int srow = lane >> 2;                      // 0..15
  int scol = ((lane & 3) ^ (srow & 3)) * 8;  // inverse-swizzled source col (shorts)
  const unsigned short* srcA = xc + (size_t)(base + m0 + 16 * w + srow) * H_DIM + scol;
  const unsigned short* srcG = gate_bf + (size_t)(e * I_DIM + n0 + 16 * w + srow) * H_DIM + scol;
  const unsigned short* srcU = up_bf   + (size_t)(e * I_DIM + n0 + 16 * w + srow) * H_DIM + scol;
  const int ldA = w * 512;            // + kh*4096
  const int ldG = 8192 + w * 512;     // + kh*8192
  const int ldU = 12288 + w * 512;    // + kh*8192

  // swizzled read offsets (shorts): idx = region + kh*half + row*32 + (fg^(row&3))*8
  int offA[2][4], offB[2][4];
#pragma unroll
  for (int kh = 0; kh < 2; ++kh) {
#pragma unroll
    for (int m = 0; m < 4; ++m) {
      int row = wm * 64 + m * 16 + fr;
      offA[kh][m] = kh * 4096 + row * 32 + ((fg ^ (row & 3)) << 3);
    }
#pragma unroll
    for (int jn = 0; jn < 4; ++jn) {
      int brow = (jn < 2) ? (wn * 32 + jn * 16 + fr) : (128 + wn * 32 + (jn - 2) * 16 + fr);
      offB[kh][jn] = 8192 + kh * 8192 + brow * 32 + ((fg ^ (brow & 3)) << 3);
    }
  }

  f32x4 acc[4][4] = {};   // [m][jn]: jn 0,1 = G; 2,3 = U

#define STG1(buf, t, kh)                                            \
  do {                                                              \
    gload16(srcA + (t) * 64 + (kh) * 32, &ls[buf][ldA + (kh) * 4096]); \
    gload16(srcG + (t) * 64 + (kh) * 32, &ls[buf][ldG + (kh) * 8192]); \
    gload16(srcU + (t) * 64 + (kh) * 32, &ls[buf][ldU + (kh) * 8192]); \
  } while (0)

  STG1(0, 0, 0);
  STG1(0, 0, 1);
  asm volatile("s_waitcnt vmcnt(3)" ::: "memory");
  __builtin_amdgcn_s_barrier();

  for (int t = 0; t < 16; ++t) {
    int cb = t & 1;
    // ---- phase kh0
    if (t + 1 < 16) STG1(cb ^ 1, t + 1, 0);
    {
      bf16x8 af[4], bf[4];
#pragma unroll
      for (int m = 0; m < 4; ++m) af[m] = *(const bf16x8*)&ls[cb][offA[0][m]];
#pragma unroll
      for (int jn = 0; jn < 4; ++jn) bf[jn] = *(const bf16x8*)&ls[cb][offB[0][jn]];
#pragma unroll
      for (int m = 0; m < 4; ++m)
#pragma unroll
        for (int jn = 0; jn < 4; ++jn)
          acc[m][jn] = __builtin_amdgcn_mfma_f32_16x16x32_bf16(af[m], bf[jn], acc[m][jn], 0, 0, 0);
    }
    if (t + 1 < 16) asm volatile("s_waitcnt vmcnt(3)" ::: "memory");
    else            asm volatile("s_waitcnt vmcnt(0)" ::: "memory");
    __builtin_amdgcn_s_barrier();
    // ---- phase kh1
    if (t + 1 < 16) STG1(cb ^ 1, t + 1, 1);
    {
      bf16x8 af[4], bf[4];
#pragma unroll
      for (int m = 0; m < 4; ++m) af[m] = *(const bf16x8*)&ls[cb][offA[1][m]];
#pragma unroll
      for (int jn = 0; jn < 4; ++jn) bf[jn] = *(const bf16x8*)&ls[cb][offB[1][jn]];
#pragma unroll
      for (int m = 0; m < 4; ++m)
#pragma unroll
        for (int jn = 0; jn < 4; ++jn)
          acc[m][jn] = __builtin_amdgcn_mfma_f32_16x16x32_bf16(af[m], bf[jn], acc[m][jn], 0, 0, 0);
    }
    if (t + 1 < 16) asm volatile("s_waitcnt vmcnt(3)" ::: "memory");
    else            asm volatile("s_waitcnt vmcnt(0)" ::: "memory");
    __builtin_amdgcn_s_barrier();
  }
#undef STG1

#pragma unroll
  for (int m = 0; m < 4; ++m)
#pragma unroll
    for (int j = 0; j < 4; ++j) {
      int row = wm * 64 + m * 16 + fg * 4 + j;  // C/D: col=lane&15, row=(lane>>4)*4+reg
      size_t rb2 = (size_t)(base + m0 + row) * I_DIM + n0;
#pragma unroll
      for (int jn = 0; jn < 2; ++jn) {
        float g = acc[m][jn][j];
        float u = acc[m][jn + 2][j];
        h[rb2 + wn * 32 + jn * 16 + fr] = (unsigned short)f2bf(g * u / (1.f + __expf(-g)));
      }
    }
}

// ---- gemm2: out[t] += w * (h_e down^T). Tile 128x128, BK=64, 256 thr/4 waves (2x2),
// wave tile 64x64. Same half-K phase pipeline, vmcnt(4). LDS dbuf 2 x 32KB -> 2 blk/CU.
// grid = 8e * 16mt * 8nt = 1024.
__global__ __launch_bounds__(256, 2) void moe_gemm2(
    const unsigned short* __restrict__ h, const unsigned short* __restrict__ wbf,
    const int* __restrict__ wsI, const float* __restrict__ routw,
    float* __restrict__ out) {
  int e = blockIdx.x & 7, rr = blockIdx.x >> 3;
  int mt = rr & 15, nt = rr >> 4;       // nt 0..7
  int cnt = wsI[e];
  int m0 = mt * 128;
  if (m0 >= cnt) return;
  int base = ebase(wsI, e);
  int n0 = nt * 128;
  const unsigned short* down_bf = wbf + 2 * WPE;

  // shorts per buffer (16384 = 32KB): A kh0 @0, A kh1 @4096, B kh0 @8192, B kh1 @12288
  __shared__ unsigned short ls[2][16384];

  int tid = threadIdx.x, lane = tid & 63, w = tid >> 6;   // 4 waves
  int wm = w >> 1, wn = w & 1;
  int fr = lane & 15, fg = lane >> 4;

  int srow = lane >> 2;
  int scol = ((lane & 3) ^ (srow & 3)) * 8;
  const unsigned short* srcA1 = h + (size_t)(base + m0 + 16 * w + srow) * I_DIM + scol;
  const unsigned short* srcA2 = h + (size_t)(base + m0 + 16 * (w + 4) + srow) * I_DIM + scol;
  const unsigned short* srcB1 = down_bf + (size_t)(e * H_DIM + n0 + 16 * w + srow) * I_DIM + scol;
  const unsigned short* srcB2 = down_bf + (size_t)(e * H_DIM + n0 + 16 * (w + 4) + srow) * I_DIM + scol;
  const int ldA1 = w * 512;              // + kh*4096
  const int ldA2 = (w + 4) * 512;
  const int ldB1 = 8192 + w * 512;       // + kh*4096
  const int ldB2 = 8192 + (w + 4) * 512;

  int offA[2][4], offB[2][4];
#pragma unroll
  for (int kh = 0; kh < 2; ++kh) {
#pragma unroll
    for (int m = 0; m < 4; ++m) {
      int row = wm * 64 + m * 16 + fr;
      offA[kh][m] = kh * 4096 + row * 32 + ((fg ^ (row & 3)) << 3);
    }
#pragma unroll
    for (int n = 0; n < 4; ++n) {
      int row = wn * 64 + n * 16 + fr;
      offB[kh][n] = 8192 + kh * 4096 + row * 32 + ((fg ^ (row & 3)) << 3);
    }
  }

  f32x4 acc[4][4] = {};

#define STG2(buf, t, kh)                                               \
  do {                                                                 \
    gload16(srcA1 + (t) * 64 + (kh) * 32, &ls[buf][ldA1 + (kh) * 4096]); \
    gload16(srcA2 + (t) * 64 + (kh) * 32, &ls[buf][ldA2 + (kh) * 4096]); \
    gload16(srcB1 + (t) * 64 + (kh) * 32, &ls[buf][ldB1 + (kh) * 4096]); \
    gload16(srcB2 + (t) * 64 + (kh) * 32, &ls[buf][ldB2 + (kh) * 4096]); \
  } while (0)

  STG2(0, 0, 0);
  STG2(0, 0, 1);
  asm volatile("s_waitcnt vmcnt(4)" ::: "memory");
  __builtin_amdgcn_s_barrier();

  for (int t = 0; t < 12; ++t) {
    int cb = t & 1;
    if (t + 1 < 12) STG2(cb ^ 1, t + 1, 0);
    {
      bf16x8 af[4], bf[4];
#pragma unroll
      for (int m = 0; m < 4; ++m) af[m] = *(const bf16x8*)&ls[cb][offA[0][m]];
#pragma unroll
      for (int n = 0; n < 4; ++n) bf[n] = *(const bf16x8*)&ls[cb][offB[0][n]];
#pragma unroll
      for (int m = 0; m < 4; ++m)
#pragma unroll
        for (int n = 0; n < 4; ++n)
          acc[m][n] = __builtin_amdgcn_mfma_f32_16x16x32_bf16(af[m], bf[n], acc[m][n], 0, 0, 0);
    }
    if (t + 1 < 12) asm volatile("s_waitcnt vmcnt(4)" ::: "memory");
    else            asm volatile("s_waitcnt vmcnt(0)" ::: "memory");
    __builtin_amdgcn_s_barrier();
    if (t + 1 < 12) STG2(cb ^ 1, t + 1, 1);
    {
      bf16x8 af[4], bf[4];
#pragma unroll
      for (int m = 0; m < 4; ++m) af[m] = *(const bf16x8*)&ls[cb][offA[1][m]];
#pragma unroll
      for (int n = 0; n < 4; ++n) bf[n] = *(const bf16x8*)&ls[cb][offB[1][n]];
#pragma unroll
      for (int m = 0; m < 4; ++m)
#pragma unroll
        for (int n = 0; n < 4; ++n)
          acc[m][n] = __builtin_amdgcn_mfma_f32_16x16x32_bf16(af[m], bf[n], acc[m][n], 0, 0, 0);
    }
    if (t + 1 < 12) asm volatile("s_waitcnt vmcnt(4)" ::: "memory");
    else            asm volatile("s_waitcnt vmcnt(0)" ::: "memory");
    __builtin_amdgcn_s_barrier();
  }
#undef STG2

#pragma unroll
  for (int m = 0; m < 4; ++m)
#pragma unroll
    for (int j = 0; j < 4; ++j) {
      int row = wm * 64 + m * 16 + fg * 4 + j;
      int grow = m0 + row;
      if (grow < cnt) {
        int tk = wsI[64 + e * T_TOK + grow];
        float rw = routw[(size_t)tk * NEXP + e];
        float* orow = out + (size_t)tk * H_DIM + n0 + wn * 64;
#pragma unroll
        for (int n = 0; n < 4; ++n)
          atomicAdd(orow + n * 16 + fr, acc[m][n][j] * rw);
      }
    }
}

extern "C" void kernel_launch(void* const* d_in, const int* in_sizes, int n_in,
                              void* d_out, int out_size, void* d_ws, size_t ws_size,
                              hipStream_t stream) {
  const float* x      = (const float*)d_in[0];
  const float* gate_w = (const float*)d_in[1];
  const float* up_w   = (const float*)d_in[2];
  const float* down_w = (const float*)d_in[3];
  const float* routw  = (const float*)d_in[4];
  float* out = (float*)d_out;
  int* wsI = (int*)d_ws;

  unsigned short* wbf = (unsigned short*)((char*)d_ws + 131072);
  unsigned short* xc  = (unsigned short*)((char*)d_ws + 37879808);
  unsigned short* h   = (unsigned short*)((char*)d_ws + 48365568);

  prep<<<3336, 512, 0, stream>>>(routw, gate_w, up_w, down_w, wbf, out, wsI);
  xgather<<<4096, 256, 0, stream>>>(x, wsI, xc);
  moe_gemm1<<<768, 512, 0, stream>>>(xc, wbf, wsI, h);
  moe_gemm2<<<1024, 256, 0, stream>>>(h, wbf, wsI, routw, out);
}

// Round 9
// 87.187 us; speedup vs baseline: 1.5177x; 1.0563x over previous
//
#include <hip/hip_runtime.h>
#include <hip/hip_bf16.h>

#define T_TOK 2048
#define H_DIM 1024
#define I_DIM 768
#define NEXP  8
#define WPE   6291456   // weight elems per array (E*I*H)

typedef short bf16x8  __attribute__((ext_vector_type(8)));
typedef short short4v __attribute__((ext_vector_type(4)));
typedef float f32x4   __attribute__((ext_vector_type(4)));

__device__ __forceinline__ short f2bf(float f) {
  __bf16 b = (__bf16)f;
  return __builtin_bit_cast(short, b);
}
__device__ __forceinline__ void gload16(const void* g, void* l) {
  __builtin_amdgcn_global_load_lds(
      (const __attribute__((address_space(1))) void*)g,
      (__attribute__((address_space(3))) void*)l, 16, 0, 0);
}
__device__ __forceinline__ int padcnt(int c) { return (c + 127) & ~127; }
__device__ __forceinline__ int ebase(const int* __restrict__ cnts, int e) {
  int b = 0;
#pragma unroll
  for (int i = 0; i < NEXP; ++i)
    if (i < e) b += padcnt(cnts[i]);
  return b;
}

// ws layout: 0: counts[8] | 256: lists[8*2048 ints] | 131072: wbf (gate++up++down bf16)
// 37879808: xc | 48365568: h

// ---- kernel A: routing compaction (8 blocks x 512)
__global__ __launch_bounds__(512) void compact_k(const float* __restrict__ routw,
                                                 int* __restrict__ wsI) {
  __shared__ int sc[8];
  int e = blockIdx.x, lane = threadIdx.x & 63, w = threadIdx.x >> 6;
  unsigned long long mk[4];
  int cnt = 0;
#pragma unroll
  for (int c = 0; c < 4; ++c) {
    int tk = w * 256 + c * 64 + lane;
    float v = routw[(size_t)tk * NEXP + e];
    mk[c] = __ballot(v > 0.f);
    cnt += __popcll(mk[c]);
  }
  if (lane == 0) sc[w] = cnt;
  __syncthreads();
  int run = 0;
#pragma unroll
  for (int j = 0; j < 8; ++j)
    if (j < w) run += sc[j];
#pragma unroll
  for (int c = 0; c < 4; ++c) {
    int tk = w * 256 + c * 64 + lane;
    if ((mk[c] >> lane) & 1ull) {
      int pos = __popcll(mk[c] & ((1ull << lane) - 1));
      wsI[64 + e * T_TOK + run + pos] = tk;
    }
    run += __popcll(mk[c]);
  }
  if (w == 7 && lane == 0) wsI[e] = run;
}

// ---- kernel B: xgather (blocks 0..4095) + gate/up conv (4096..7167), 256 thr
__global__ __launch_bounds__(256) void gatherconv_k(const float* __restrict__ x,
                                                    const float* __restrict__ gw,
                                                    const float* __restrict__ uw,
                                                    const int* __restrict__ wsI,
                                                    unsigned short* __restrict__ xc,
                                                    unsigned short* __restrict__ wbf) {
  int bid = blockIdx.x;
  if (bid < 4096) {            // xgather: 4 rows/block
    int e = bid >> 9, rb = bid & 511;
    int cnt = wsI[e];
    int pad = padcnt(cnt);
    int r = rb * 4 + (threadIdx.x >> 6);
    if (r >= pad) return;
    int base = ebase(wsI, e);
    int col = (threadIdx.x & 63) * 16;
    unsigned short* dst = xc + (size_t)(base + r) * H_DIM + col;
    if (r < cnt) {
      int tok = wsI[64 + e * T_TOK + r];
      const float* sr = x + (size_t)tok * H_DIM + col;
#pragma unroll
      for (int j = 0; j < 4; ++j) {
        float4 v = *(const float4*)(sr + j * 4);
        short4v b = {f2bf(v.x), f2bf(v.y), f2bf(v.z), f2bf(v.w)};
        *(short4v*)(dst + j * 4) = b;
      }
    } else {
#pragma unroll
      for (int j = 0; j < 4; ++j) {
        short4v z = {0, 0, 0, 0};
        *(short4v*)(dst + j * 4) = z;
      }
    }
  } else {                     // gate+up fp32->bf16
    size_t off = ((size_t)(bid - 4096) * 256 + threadIdx.x) * 16;
    int a = (off >= (size_t)WPE) ? 1 : 0;
    size_t rem = off - (size_t)a * WPE;
    const float* s = (a ? uw : gw) + rem;
    unsigned short* o = wbf + (size_t)a * WPE + rem;
#pragma unroll
    for (int j = 0; j < 4; ++j) {
      float4 v = *(const float4*)(s + j * 4);
      short4v b = {f2bf(v.x), f2bf(v.y), f2bf(v.z), f2bf(v.w)};
      *(short4v*)(o + j * 4) = b;
    }
  }
}

// ---- shared pipeline macros (depth-5 half-buffer ring, 3 loads/half/wave) ----
#define WB(v)                                              \
  do {                                                     \
    asm volatile("s_waitcnt vmcnt(" #v ")" ::: "memory");  \
    __builtin_amdgcn_s_barrier();                          \
    __builtin_amdgcn_sched_barrier(0);                     \
  } while (0)

// ---- kernel C: gemm1 (blocks 0..767) + down-conv (768..1535) + zerofill (1536..1791)
// gemm1: h = silu(Xc Wg^T)*(Xc Wu^T). Tile M128 x (G128++U128), half-K=32 phases (NH=32),
// 8 waves (2Mx4N), wave tile 64x64. 5 half-bufs, stage 4 ahead, vmcnt(6), 1 barrier/phase.
__global__ __launch_bounds__(512, 2) void gemm1_k(
    const unsigned short* __restrict__ xc, unsigned short* __restrict__ wbf,
    const int* __restrict__ wsI, unsigned short* __restrict__ h,
    const float* __restrict__ dw, float* __restrict__ out) {
  int bid = blockIdx.x;
  if (bid >= 768) {
    if (bid < 1536) {          // down fp32->bf16 (runs while gemm1 computes; used by gemm2)
      size_t off = ((size_t)(bid - 768) * 512 + threadIdx.x) * 16;
      const float* s = dw + off;
      unsigned short* o = wbf + 2 * (size_t)WPE + off;
#pragma unroll
      for (int j = 0; j < 4; ++j) {
        float4 v = *(const float4*)(s + j * 4);
        short4v b = {f2bf(v.x), f2bf(v.y), f2bf(v.z), f2bf(v.w)};
        *(short4v*)(o + j * 4) = b;
      }
    } else {                   // zerofill out (used by gemm2)
      size_t off = ((size_t)(bid - 1536) * 512 + threadIdx.x) * 16;
      f32x4 z = {0.f, 0.f, 0.f, 0.f};
#pragma unroll
      for (int j = 0; j < 4; ++j) *(f32x4*)(out + off + j * 4) = z;
    }
    return;
  }
  int e = bid & 7, rr = bid >> 3;
  int mt = rr & 15, nt = rr >> 4;       // nt 0..5
  int cnt = wsI[e];
  int m0 = mt * 128;
  if (m0 >= cnt) return;
  int base = ebase(wsI, e);
  int n0 = nt * 128;

  __shared__ unsigned short ls[5][12288];   // per half-buf: A[128][32]@0, B[256][32]@4096

  int tid = threadIdx.x, lane = tid & 63, w = tid >> 6;
  int wm = w >> 2, wn = w & 3;
  int fr = lane & 15, fg = lane >> 4;
  int srow = lane >> 2;
  int scol = ((lane & 3) ^ (srow & 3)) * 8;   // inverse-swizzled source col

  const unsigned short* srcA = xc + (size_t)(base + m0 + 16 * w + srow) * H_DIM + scol;
  const unsigned short* srcG = wbf + (size_t)(e * I_DIM + n0 + 16 * w + srow) * H_DIM + scol;
  const unsigned short* srcU = wbf + WPE + (size_t)(e * I_DIM + n0 + 16 * w + srow) * H_DIM + scol;

  int roA[4], roB[4];
#pragma unroll
  for (int m = 0; m < 4; ++m) {
    int r2 = wm * 64 + m * 16 + fr;
    roA[m] = r2 * 32 + ((fg ^ (r2 & 3)) << 3);
  }
#pragma unroll
  for (int n = 0; n < 4; ++n) {
    int r2 = (n < 2) ? (wn * 32 + n * 16 + fr) : (128 + wn * 32 + (n - 2) * 16 + fr);
    roB[n] = 4096 + r2 * 32 + ((fg ^ (r2 & 3)) << 3);
  }

  bf16x8 af[2][4], bv[2][4];
  f32x4 acc[4][4] = {};   // [m][jn]: jn 0,1 = G cols; 2,3 = U cols

#define STG1(hh)                                                     \
  do {                                                               \
    unsigned short* lb = &ls[(hh) % 5][0];                           \
    gload16(srcA + (hh) * 32, lb + w * 512);                         \
    gload16(srcG + (hh) * 32, lb + 4096 + w * 512);                  \
    gload16(srcU + (hh) * 32, lb + 4096 + (w + 8) * 512);            \
  } while (0)
#define LDF1(st, hh)                                                 \
  do {                                                               \
    const unsigned short* lb = &ls[(hh) % 5][0];                     \
    _Pragma("unroll") for (int m = 0; m < 4; ++m) af[st][m] = *(const bf16x8*)(lb + roA[m]); \
    _Pragma("unroll") for (int n = 0; n < 4; ++n) bv[st][n] = *(const bf16x8*)(lb + roB[n]); \
  } while (0)
#define MM1(st)                                                      \
  do {                                                               \
    __builtin_amdgcn_s_setprio(1);                                   \
    _Pragma("unroll") for (int m = 0; m < 4; ++m)                    \
      _Pragma("unroll") for (int n = 0; n < 4; ++n)                  \
        acc[m][n] = __builtin_amdgcn_mfma_f32_16x16x32_bf16(af[st][m], bv[st][n], acc[m][n], 0, 0, 0); \
    __builtin_amdgcn_s_setprio(0);                                   \
  } while (0)

  STG1(0); STG1(1); STG1(2); STG1(3);
  WB(6);                       // halves 0,1 landed; 2,3 in flight
  LDF1(0, 0);
#pragma unroll
  for (int i = 0; i < 32; ++i) {
    if (i + 4 < 32) STG1(i + 4);
    if (i + 1 < 32) LDF1((i + 1) & 1, i + 1);
    MM1(i & 1);
    if (i <= 27)      WB(6);
    else if (i == 28) WB(3);
    else if (i == 29) WB(0);
  }
#undef STG1
#undef LDF1
#undef MM1

#pragma unroll
  for (int m = 0; m < 4; ++m)
#pragma unroll
    for (int j = 0; j < 4; ++j) {
      int row = wm * 64 + m * 16 + fg * 4 + j;   // C/D: col=lane&15, row=(lane>>4)*4+reg
      size_t rb2 = (size_t)(base + m0 + row) * I_DIM + n0;
#pragma unroll
      for (int jn = 0; jn < 2; ++jn) {
        float g = acc[m][jn][j];
        float u = acc[m][jn + 2][j];
        h[rb2 + wn * 32 + jn * 16 + fr] = (unsigned short)f2bf(g * u / (1.f + __expf(-g)));
      }
    }
}

// ---- kernel D: gemm2: out[t] += w * (h_e down^T). Tile M128 x N256, NH=24,
// 8 waves (2Mx4N), wave tile 64x64, same depth-5 pipeline. grid 8*16*4=512.
__global__ __launch_bounds__(512, 2) void gemm2_k(
    const unsigned short* __restrict__ h, const unsigned short* __restrict__ wbf,
    const int* __restrict__ wsI, const float* __restrict__ routw,
    float* __restrict__ out) {
  int e = blockIdx.x & 7, rr = blockIdx.x >> 3;
  int mt = rr & 15, nt = rr >> 4;       // nt 0..3
  int cnt = wsI[e];
  int m0 = mt * 128;
  if (m0 >= cnt) return;
  int base = ebase(wsI, e);
  int n0 = nt * 256;
  const unsigned short* down_bf = wbf + 2 * (size_t)WPE;

  __shared__ unsigned short ls[5][12288];   // A[128][32]@0, B[256][32]@4096

  int tid = threadIdx.x, lane = tid & 63, w = tid >> 6;
  int wm = w >> 2, wn = w & 3;
  int fr = lane & 15, fg = lane >> 4;
  int srow = lane >> 2;
  int scol = ((lane & 3) ^ (srow & 3)) * 8;

  const unsigned short* srcA  = h + (size_t)(base + m0 + 16 * w + srow) * I_DIM + scol;
  const unsigned short* srcB1 = down_bf + (size_t)(e * H_DIM + n0 + 16 * w + srow) * I_DIM + scol;
  const unsigned short* srcB2 = down_bf + (size_t)(e * H_DIM + n0 + 16 * (w + 8) + srow) * I_DIM + scol;

  int roA[4], roB[4];
#pragma unroll
  for (int m = 0; m < 4; ++m) {
    int r2 = wm * 64 + m * 16 + fr;
    roA[m] = r2 * 32 + ((fg ^ (r2 & 3)) << 3);
  }
#pragma unroll
  for (int n = 0; n < 4; ++n) {
    int r2 = wn * 64 + n * 16 + fr;
    roB[n] = 4096 + r2 * 32 + ((fg ^ (r2 & 3)) << 3);
  }

  bf16x8 af[2][4], bv[2][4];
  f32x4 acc[4][4] = {};

#define STG2(hh)                                                     \
  do {                                                               \
    unsigned short* lb = &ls[(hh) % 5][0];                           \
    gload16(srcA + (hh) * 32, lb + w * 512);                         \
    gload16(srcB1 + (hh) * 32, lb + 4096 + w * 512);                 \
    gload16(srcB2 + (hh) * 32, lb + 4096 + (w + 8) * 512);           \
  } while (0)
#define LDF2(st, hh)                                                 \
  do {                                                               \
    const unsigned short* lb = &ls[(hh) % 5][0];                     \
    _Pragma("unroll") for (int m = 0; m < 4; ++m) af[st][m] = *(const bf16x8*)(lb + roA[m]); \
    _Pragma("unroll") for (int n = 0; n < 4; ++n) bv[st][n] = *(const bf16x8*)(lb + roB[n]); \
  } while (0)
#define MM2(st)                                                      \
  do {                                                               \
    __builtin_amdgcn_s_setprio(1);                                   \
    _Pragma("unroll") for (int m = 0; m < 4; ++m)                    \
      _Pragma("unroll") for (int n = 0; n < 4; ++n)                  \
        acc[m][n] = __builtin_amdgcn_mfma_f32_16x16x32_bf16(af[st][m], bv[st][n], acc[m][n], 0, 0, 0); \
    __builtin_amdgcn_s_setprio(0);                                   \
  } while (0)

  STG2(0); STG2(1); STG2(2); STG2(3);
  WB(6);
  LDF2(0, 0);
#pragma unroll
  for (int i = 0; i < 24; ++i) {
    if (i + 4 < 24) STG2(i + 4);
    if (i + 1 < 24) LDF2((i + 1) & 1, i + 1);
    MM2(i & 1);
    if (i <= 19)      WB(6);
    else if (i == 20) WB(3);
    else if (i == 21) WB(0);
  }
#undef STG2
#undef LDF2
#undef MM2

#pragma unroll
  for (int m = 0; m < 4; ++m)
#pragma unroll
    for (int j = 0; j < 4; ++j) {
      int row = wm * 64 + m * 16 + fg * 4 + j;
      int grow = m0 + row;
      if (grow < cnt) {
        int tk = wsI[64 + e * T_TOK + grow];
        float rw = routw[(size_t)tk * NEXP + e];
        float* orow = out + (size_t)tk * H_DIM + n0 + wn * 64;
#pragma unroll
        for (int n = 0; n < 4; ++n)
          atomicAdd(orow + n * 16 + fr, acc[m][n][j] * rw);
      }
    }
}

extern "C" void kernel_launch(void* const* d_in, const int* in_sizes, int n_in,
                              void* d_out, int out_size, void* d_ws, size_t ws_size,
                              hipStream_t stream) {
  const float* x      = (const float*)d_in[0];
  const float* gate_w = (const float*)d_in[1];
  const float* up_w   = (const float*)d_in[2];
  const float* down_w = (const float*)d_in[3];
  const float* routw  = (const float*)d_in[4];
  float* out = (float*)d_out;
  int* wsI = (int*)d_ws;

  unsigned short* wbf = (unsigned short*)((char*)d_ws + 131072);
  unsigned short* xc  = (unsigned short*)((char*)d_ws + 37879808);
  unsigned short* h   = (unsigned short*)((char*)d_ws + 48365568);

  compact_k<<<8, 512, 0, stream>>>(routw, wsI);
  gatherconv_k<<<7168, 256, 0, stream>>>(x, gate_w, up_w, wsI, xc, wbf);
  gemm1_k<<<1792, 512, 0, stream>>>(xc, wbf, wsI, h, down_w, out);
  gemm2_k<<<512, 512, 0, stream>>>(h, wbf, wsI, routw, out);
}